// Round 4
// baseline (334.652 us; speedup 1.0000x reference)
//
#include <hip/hip_runtime.h>
#include <hip/hip_bf16.h>

#define NTOK 49
#define CDIM 128
#define C3   384
#define NHEAD 4
#define HDIM 32
#define SCALE 0.17677669529663687f
#define LOG2E 1.4426950408889634f
#define SC2   (0.17677669529663687f * 1.4426950408889634f)
#define QS2 132   // x/o and k row stride, elems (264 B: 66 words == 2 banks/row -> even b128 spread)
#define TSV 52    // vT token stride (104 B rows, 8B-aligned)

typedef __attribute__((ext_vector_type(8))) __bf16 bf16x8;
typedef __attribute__((ext_vector_type(4))) __bf16 bf16x4;
typedef __attribute__((ext_vector_type(4))) float f32x4;

__device__ __forceinline__ f32x4 mfma32(bf16x8 a, bf16x8 b, f32x4 c) {
  return __builtin_amdgcn_mfma_f32_16x16x32_bf16(a, b, c, 0, 0, 0);
}
// K=16 semantics emulated on x32: j=0..3 real, j=4..7 dead (one operand zero-padded,
// the other dup'd so the dead half is defined-finite).
__device__ __forceinline__ bf16x8 dup8(bf16x4 t) {
  uint2 w = __builtin_bit_cast(uint2, t);
  uint4 r; r.x = w.x; r.y = w.y; r.z = w.x; r.w = w.y;
  return __builtin_bit_cast(bf16x8, r);
}
__device__ __forceinline__ bf16x8 zpad8(bf16x4 t) {
  uint2 w = __builtin_bit_cast(uint2, t);
  uint4 r; r.x = w.x; r.y = w.y; r.z = 0u; r.w = 0u;
  return __builtin_bit_cast(bf16x8, r);
}
__device__ __forceinline__ unsigned pkbf(float lo, float hi) {
  unsigned short a = __builtin_bit_cast(unsigned short, (__bf16)lo);
  unsigned short b = __builtin_bit_cast(unsigned short, (__bf16)hi);
  return ((unsigned)b << 16) | (unsigned)a;
}

// ws layout (bytes):
//   qkvT  __bf16[384][128] @ 0       qkvT[n][k] = qkv_w[k][n]; q rows pre-scaled by SCALE*LOG2E
//   projT __bf16[128][128] @ 98304
//   blut  float [4][64][64]@ 131072  rel-bias LUT [h][q][k] * LOG2E, k>=49 -> -1.44e30

__global__ __launch_bounds__(256) void prep_kernel(
    const float* __restrict__ qkv_w, const float* __restrict__ proj_w,
    const float* __restrict__ bias_table,
    __bf16* __restrict__ qkvT, __bf16* __restrict__ projT, float* __restrict__ blut)
{
  int o = blockIdx.x * 256 + threadIdx.x;
  if (o < CDIM * C3) {
    int k = o / C3, n = o - k * C3;
    float v = qkv_w[o];
    if (n < CDIM) v *= SC2;                // fold softmax scale AND log2e into q weights
    qkvT[n * CDIM + k] = (__bf16)v;
  } else if (o < CDIM * C3 + CDIM * CDIM) {
    int o2 = o - CDIM * C3;
    int k = o2 >> 7, n = o2 & 127;
    projT[n * CDIM + k] = (__bf16)proj_w[o2];
  } else if (o < CDIM * C3 + CDIM * CDIM + NHEAD * 64 * 64) {
    int t3 = o - (CDIM * C3 + CDIM * CDIM);
    int hh = t3 >> 12, r = (t3 >> 6) & 63, c = t3 & 63;
    float v;
    if (c >= NTOK) v = -1e30f;             // softmax mask for padded key columns
    else if (r >= NTOK) v = 0.0f;          // padded query rows: finite, never stored
    else {
      int idx = (r / 7 - c / 7 + 6) * 13 + (r % 7 - c % 7 + 6);
      v = bias_table[idx * NHEAD + hh];
    }
    blut[t3] = v * LOG2E;                  // fold log2e -> exp2 in kernel
  }
}

// 512 threads = 8 waves. LDS 39184 B. launch_bounds(512,6) caps unified regfile ~84:
// k/v passes split and proj weights loaded late so peak demand fits WITHOUT spill.
// 3 barriers. q and P never touch LDS.
__global__ __launch_bounds__(512, 6) void attn_kernel(
    const float* __restrict__ x, const float* __restrict__ qkv_b,
    const float* __restrict__ proj_b, const char* __restrict__ ws,
    float* __restrict__ out)
{
  __shared__ __align__(16) char smem[39184];
  char*   xo_ = smem;                      // [49][132] bf16: x tile, later O tile
  char*   ks_ = smem + 12936;              // [49][132] bf16: K[tok][ch]
  __bf16* vT_ = (__bf16*)(smem + 25872);   // [128][52]  bf16: V^T[ch][tok], cols 49..51 zeroed

  const __bf16* qkvT  = (const __bf16*)ws;
  const __bf16* projT = (const __bf16*)(ws + 98304);
  const float*  blut  = (const float*)(ws + 131072);

  const int tid  = threadIdx.x;
  const int wave = tid >> 6;
  const int lane = tid & 63;
  const int l15  = lane & 15;
  const int lg   = lane >> 4;
  const int h    = wave & 3, mhalf = wave >> 2;
  const int hc   = h * HDIM;               // head channel base
  const int chw  = wave * 16;              // k/v/proj channel base for this wave

  const int win = blockIdx.x;
  const int b  = win >> 6;
  const int wh = (win >> 3) & 7;
  const int ww = win & 7;
  const float* xbase = x + (((b * 56) + wh * 7) * 56 + ww * 7) * CDIM;

  // per-lane clamped row byte-bases for the 132-stride tiles; reused by every phase
  int rb[4];
  #pragma unroll
  for (int mt = 0; mt < 4; ++mt) {
    int t = mt * 16 + l15; if (t > 48) t = 48;
    rb[mt] = t * (QS2 * 2);
  }

  // ---- phase 0: stage x rows 0..48 into LDS bf16 [49][132] ----
  {
    int L = tid;
    #pragma unroll
    for (int p = 0; p < 2; ++p) {
      if (L < 784) {                        // 49 rows * 16 chunks
        int r = L >> 4, c = L & 15;
        const float* g = xbase + ((r / 7) * 56 + (r % 7)) * CDIM + c * 8;
        f32x4 x0 = *(const f32x4*)g;
        f32x4 x1 = *(const f32x4*)(g + 4);
        bf16x8 v8;
        v8[0] = (__bf16)x0[0]; v8[1] = (__bf16)x0[1]; v8[2] = (__bf16)x0[2]; v8[3] = (__bf16)x0[3];
        v8[4] = (__bf16)x1[0]; v8[5] = (__bf16)x1[1]; v8[6] = (__bf16)x1[2]; v8[7] = (__bf16)x1[3];
        *(bf16x8*)(xo_ + r * (QS2 * 2) + c * 16) = v8;
      }
      L += 512;
    }
  }

  // ---- prefetch ONLY k weights (16 regs); v weights loaded after k-pass ----
  bf16x8 awk[4];
  #pragma unroll
  for (int kt = 0; kt < 4; ++kt)
    awk[kt] = *(const bf16x8*)(qkvT + (CDIM + chw + l15) * CDIM + kt * 32 + lg * 8);
  f32x4 kbv = *(const f32x4*)(qkv_b + CDIM + chw + lg * 4);

  __syncthreads();   // [1] x tile ready

  // ---- pass k: K rows = channels, cols = tokens -> b64 stores into K[tok][ch] ----
  #pragma unroll
  for (int mt = 0; mt < 4; ++mt) {
    const int tok = mt * 16 + l15;
    bf16x8 a[4];
    #pragma unroll
    for (int kt = 0; kt < 4; ++kt)
      a[kt] = *(const bf16x8*)(xo_ + rb[mt] + kt * 64 + lg * 16);
    f32x4 ck; ck[0]=0.f; ck[1]=0.f; ck[2]=0.f; ck[3]=0.f;
    #pragma unroll
    for (int kt = 0; kt < 4; ++kt) ck = mfma32(awk[kt], a[kt], ck);
    if (tok <= 48) {
      bf16x4 k4;
      #pragma unroll
      for (int i = 0; i < 4; ++i) k4[i] = (__bf16)(ck[i] + kbv[i]);
      *(bf16x4*)(ks_ + tok * (QS2 * 2) + (chw + lg * 4) * 2) = k4;
    }
  }

  // ---- pass v: load awv now (awk dead), store V^T[ch][tok] ----
  {
    bf16x8 awv[4];
    #pragma unroll
    for (int kt = 0; kt < 4; ++kt)
      awv[kt] = *(const bf16x8*)(qkvT + (2 * CDIM + chw + l15) * CDIM + kt * 32 + lg * 8);
    f32x4 vbv = *(const f32x4*)(qkv_b + 2 * CDIM + chw + lg * 4);
    #pragma unroll
    for (int mt = 0; mt < 4; ++mt) {
      const int tok = mt * 16 + l15;
      bf16x8 a[4];
      #pragma unroll
      for (int kt = 0; kt < 4; ++kt)
        a[kt] = *(const bf16x8*)(xo_ + rb[mt] + kt * 64 + lg * 16);
      f32x4 cv; cv[0]=0.f; cv[1]=0.f; cv[2]=0.f; cv[3]=0.f;
      #pragma unroll
      for (int kt = 0; kt < 4; ++kt) cv = mfma32(awv[kt], a[kt], cv);
      if (tok <= 48) {
        #pragma unroll
        for (int i = 0; i < 4; ++i)
          vT_[(chw + lg * 4 + i) * TSV + tok] = (__bf16)(cv[i] + vbv[i]);
      } else if (tok <= 51) {               // zero-fill vT cols 49..51 (clamped PV load reach)
        #pragma unroll
        for (int i = 0; i < 4; ++i)
          vT_[(chw + lg * 4 + i) * TSV + tok] = (__bf16)0.0f;
      }
    }
  }

  // ---- pass q: this wave's own head+half, kept in registers (packed bf16 pairs) ----
  int rbq[2];
  rbq[0] = mhalf ? rb[2] : rb[0];
  rbq[1] = mhalf ? rb[3] : rb[1];
  unsigned pkq[2][2][2];                   // [mi][ct][t]: Q^T[ch=hc+ct*16+lg*4+2t{,+1}][q]
  #pragma unroll
  for (int ct = 0; ct < 2; ++ct) {
    bf16x8 awq[4];
    #pragma unroll
    for (int kt = 0; kt < 4; ++kt)
      awq[kt] = *(const bf16x8*)(qkvT + (hc + ct * 16 + l15) * CDIM + kt * 32 + lg * 8);
    f32x4 qbv = *(const f32x4*)(qkv_b + hc + ct * 16 + lg * 4);
    #pragma unroll
    for (int mi = 0; mi < 2; ++mi) {
      bf16x8 a[4];
      #pragma unroll
      for (int kt = 0; kt < 4; ++kt)
        a[kt] = *(const bf16x8*)(xo_ + rbq[mi] + kt * 64 + lg * 16);
      f32x4 qc; qc[0]=0.f; qc[1]=0.f; qc[2]=0.f; qc[3]=0.f;
      #pragma unroll
      for (int kt = 0; kt < 4; ++kt) qc = mfma32(awq[kt], a[kt], qc);
      pkq[mi][ct][0] = pkbf(qc[0] + qbv[0] * SC2, qc[1] + qbv[1] * SC2);
      pkq[mi][ct][1] = pkbf(qc[2] + qbv[2] * SC2, qc[3] + qbv[3] * SC2);
    }
  }

  __syncthreads();   // [2] K/V staged; all x reads done (O may overlay xo_)

  // ---- phase 2: attention, register-resident softmax ----
  const float* blh = blut + h * 4096;
  bf16x8 akf[4];                           // K A-frags: rows = tokens, k = 32 head channels
  #pragma unroll
  for (int nt = 0; nt < 4; ++nt)
    akf[nt] = *(const bf16x8*)(ks_ + rb[nt] + (hc + lg * 8) * 2);

  #pragma unroll
  for (int mi = 0; mi < 2; ++mi) {
    const int m0 = (2 * mhalf + mi) * 16;

    // assemble Q^T B-frag from in-register pkq via 8 bpermute + 4 select
    unsigned bqw[4];
    #pragma unroll
    for (int d = 0; d < 4; ++d) {
      int srcl = ((lg & 1) * 2 + (d >> 1)) * 16 + l15;
      unsigned w0 = __shfl(pkq[mi][0][d & 1], srcl);
      unsigned w1 = __shfl(pkq[mi][1][d & 1], srcl);
      bqw[d] = (lane >= 32) ? w1 : w0;
    }
    uint4 bqv; bqv.x = bqw[0]; bqv.y = bqw[1]; bqv.z = bqw[2]; bqv.w = bqw[3];
    bf16x8 bq8 = __builtin_bit_cast(bf16x8, bqv);

    float psum = 0.f;
    bf16x4 pa4[4];                         // P^T fragments, in-lane
    #pragma unroll
    for (int nt = 0; nt < 4; ++nt) {
      f32x4 bias = *(const f32x4*)(blh + (m0 + l15) * 64 + nt * 16 + lg * 4);
      f32x4 z; z[0]=0.f; z[1]=0.f; z[2]=0.f; z[3]=0.f;
      f32x4 s = mfma32(akf[nt], bq8, z);   // S^T[tok=nt*16+lg*4+i][q=m0+l15]
      float e0 = exp2f(s[0] + bias[0]);
      float e1 = exp2f(s[1] + bias[1]);
      float e2 = exp2f(s[2] + bias[2]);
      float e3 = exp2f(s[3] + bias[3]);
      psum += (e0 + e1) + (e2 + e3);
      uint2 pw; pw.x = pkbf(e0, e1); pw.y = pkbf(e2, e3);
      pa4[nt] = __builtin_bit_cast(bf16x4, pw);
    }
    psum += __shfl_xor(psum, 16);          // reduce over lg groups (same q column)
    psum += __shfl_xor(psum, 32);
    const float inv = __builtin_amdgcn_rcpf(psum);

    // PV as O^T = V^T * P^T, K=16 emulated (pa zero-padded, V dup-padded)
    f32x4 ot0, ot1;
    ot0[0]=0.f; ot0[1]=0.f; ot0[2]=0.f; ot0[3]=0.f;
    ot1[0]=0.f; ot1[1]=0.f; ot1[2]=0.f; ot1[3]=0.f;
    const __bf16* vrow0 = vT_ + (hc + l15) * TSV;
    const __bf16* vrow1 = vrow0 + 16 * TSV;
    #pragma unroll
    for (int nt = 0; nt < 4; ++nt) {
      int tb = nt * 16 + lg * 4; if (tb > 48) tb = 48;
      bf16x8 pb8 = zpad8(pa4[nt]);
      bf16x4 v0 = *(const bf16x4*)(vrow0 + tb);
      bf16x4 v1 = *(const bf16x4*)(vrow1 + tb);
      ot0 = mfma32(dup8(v0), pb8, ot0);
      ot1 = mfma32(dup8(v1), pb8, ot1);
    }
    const int rq = m0 + l15;
    if (rq <= 48) {
      char* orow = xo_ + rq * (QS2 * 2);
      #pragma unroll
      for (int i = 0; i < 4; ++i) {
        *(__bf16*)(orow + (hc + lg * 4 + i) * 2)      = (__bf16)(ot0[i] * inv);
        *(__bf16*)(orow + (hc + 16 + lg * 4 + i) * 2) = (__bf16)(ot1[i] * inv);
      }
    }
  }

  __syncthreads();   // [3] O ready across waves

  // ---- phase 3: proj GEMM; weights loaded HERE (post-barrier) to keep phase-2 lean ----
  bf16x8 bp[4];
  #pragma unroll
  for (int kt = 0; kt < 4; ++kt)
    bp[kt] = *(const bf16x8*)(projT + (chw + l15) * CDIM + kt * 32 + lg * 8);
  const float pb = proj_b[chw + l15];

  float* outw = out + (((b * 56) + wh * 7) * 56 + ww * 7) * CDIM;
  #pragma unroll
  for (int mt = 0; mt < 4; ++mt) {
    bf16x8 ao[4];
    #pragma unroll
    for (int kt = 0; kt < 4; ++kt)
      ao[kt] = *(const bf16x8*)(xo_ + rb[mt] + kt * 64 + lg * 16);
    f32x4 c0; c0[0]=0.f; c0[1]=0.f; c0[2]=0.f; c0[3]=0.f;
    #pragma unroll
    for (int kt = 0; kt < 4; ++kt) c0 = mfma32(ao[kt], bp[kt], c0);
    #pragma unroll
    for (int i = 0; i < 4; ++i) {
      const int r = mt * 16 + lg * 4 + i;
      if (r < NTOK) {
        float* po = outw + ((r / 7) * 56 + (r % 7)) * CDIM + chw;
        po[l15] = c0[i] + pb;
      }
    }
  }
}

extern "C" void kernel_launch(void* const* d_in, const int* in_sizes, int n_in,
                              void* d_out, int out_size, void* d_ws, size_t ws_size,
                              hipStream_t stream) {
  const float* x          = (const float*)d_in[0];
  const float* qkv_b      = (const float*)d_in[2];
  const float* proj_b     = (const float*)d_in[4];

  hipLaunchKernelGGL(prep_kernel, dim3(320), dim3(256), 0, stream,
                     (const float*)d_in[1], (const float*)d_in[3], (const float*)d_in[5],
                     (__bf16*)d_ws, (__bf16*)((char*)d_ws + 98304),
                     (float*)((char*)d_ws + 131072));
  hipLaunchKernelGGL(attn_kernel, dim3(4096), dim3(512), 0, stream,
                     x, qkv_b, proj_b, (const char*)d_ws, (float*)d_out);
}

// Round 5
// 287.211 us; speedup vs baseline: 1.1652x; 1.1652x over previous
//
#include <hip/hip_runtime.h>
#include <hip/hip_bf16.h>

#define NTOK 49
#define CDIM 128
#define C3   384
#define NHEAD 4
#define HDIM 32
#define LOG2E 1.4426950408889634f
#define SC2   (0.17677669529663687f * 1.4426950408889634f)
#define QS2 132   // x/O tile row stride, elems (264 B rows; known-good bank spread)
#define TSV 52    // per-wave vT token stride (104 B rows)
#define VTW 3328  // per-wave vT bytes: 32*52*2

typedef __attribute__((ext_vector_type(8))) __bf16 bf16x8;
typedef __attribute__((ext_vector_type(4))) __bf16 bf16x4;
typedef __attribute__((ext_vector_type(4))) float f32x4;

__device__ __forceinline__ f32x4 mfma32(bf16x8 a, bf16x8 b, f32x4 c) {
  return __builtin_amdgcn_mfma_f32_16x16x32_bf16(a, b, c, 0, 0, 0);
}
// K=16 semantics emulated on x32: j=0..3 real, j=4..7 dead (one operand zero-padded,
// the other dup'd so the dead half is defined-finite).
__device__ __forceinline__ bf16x8 dup8(bf16x4 t) {
  uint2 w = __builtin_bit_cast(uint2, t);
  uint4 r; r.x = w.x; r.y = w.y; r.z = w.x; r.w = w.y;
  return __builtin_bit_cast(bf16x8, r);
}
__device__ __forceinline__ bf16x8 zpad8(bf16x4 t) {
  uint2 w = __builtin_bit_cast(uint2, t);
  uint4 r; r.x = w.x; r.y = w.y; r.z = 0u; r.w = 0u;
  return __builtin_bit_cast(bf16x8, r);
}
__device__ __forceinline__ unsigned pkbf(float lo, float hi) {
  unsigned short a = __builtin_bit_cast(unsigned short, (__bf16)lo);
  unsigned short b = __builtin_bit_cast(unsigned short, (__bf16)hi);
  return ((unsigned)b << 16) | (unsigned)a;
}

// ws layout (bytes):
//   qkvT  __bf16[384][128] @ 0       qkvT[n][k] = qkv_w[k][n]; q rows pre-scaled by SCALE*LOG2E
//   projT __bf16[128][128] @ 98304
//   blut  float [4][64][64]@ 131072  rel-bias LUT [h][q][k] * LOG2E, k>=49 -> -1.44e30

__global__ __launch_bounds__(256) void prep_kernel(
    const float* __restrict__ qkv_w, const float* __restrict__ proj_w,
    const float* __restrict__ bias_table,
    __bf16* __restrict__ qkvT, __bf16* __restrict__ projT, float* __restrict__ blut)
{
  int o = blockIdx.x * 256 + threadIdx.x;
  if (o < CDIM * C3) {
    int k = o / C3, n = o - k * C3;
    float v = qkv_w[o];
    if (n < CDIM) v *= SC2;                // fold softmax scale AND log2e into q weights
    qkvT[n * CDIM + k] = (__bf16)v;
  } else if (o < CDIM * C3 + CDIM * CDIM) {
    int o2 = o - CDIM * C3;
    int k = o2 >> 7, n = o2 & 127;
    projT[n * CDIM + k] = (__bf16)proj_w[o2];
  } else if (o < CDIM * C3 + CDIM * CDIM + NHEAD * 64 * 64) {
    int t3 = o - (CDIM * C3 + CDIM * CDIM);
    int hh = t3 >> 12, r = (t3 >> 6) & 63, c = t3 & 63;
    float v;
    if (c >= NTOK) v = -1e30f;             // softmax mask for padded key columns
    else if (r >= NTOK) v = 0.0f;          // padded query rows: finite, never stored
    else {
      int idx = (r / 7 - c / 7 + 6) * 13 + (r % 7 - c % 7 + 6);
      v = bias_table[idx * NHEAD + hh];
    }
    blut[t3] = v * LOG2E;                  // fold log2e -> exp2 in kernel
  }
}

// 256 threads = 4 waves; wave h owns head h end-to-end (its 32 q/k/v channels).
// K,Q transposed in-register via shuffles; V via wave-local LDS strip; P in regs.
// LDS 26248 B; launch_bounds(256,4) caps regs at 128 -> structurally spill-free.
__global__ __launch_bounds__(256, 4) void attn_kernel(
    const float* __restrict__ x, const float* __restrict__ qkv_b,
    const float* __restrict__ proj_b, const char* __restrict__ ws,
    float* __restrict__ out)
{
  __shared__ __align__(16) char smem[26248];
  char* xo_ = smem;                        // [49][132] bf16: x tile, later O tile

  const __bf16* qkvT  = (const __bf16*)ws;
  const __bf16* projT = (const __bf16*)(ws + 98304);
  const float*  blut  = (const float*)(ws + 131072);

  const int tid  = threadIdx.x;
  const int wave = tid >> 6;               // 0..3 == head
  const int lane = tid & 63;
  const int l15  = lane & 15;
  const int lg   = lane >> 4;
  const int hc   = wave * HDIM;            // this wave's 32-channel base
  __bf16* vTw = (__bf16*)(smem + 12936 + wave * VTW);  // [32][52] V^T strip

  const int win = blockIdx.x;
  const int b  = win >> 6;
  const int wh = (win >> 3) & 7;
  const int ww = win & 7;
  const float* xbase = x + (((b * 56) + wh * 7) * 56 + ww * 7) * CDIM;

  // per-lane clamped row byte-bases into the 132-stride tile
  int rb[4];
  #pragma unroll
  for (int mt = 0; mt < 4; ++mt) {
    int t = mt * 16 + l15; if (t > 48) t = 48;
    rb[mt] = t * (QS2 * 2);
  }

  // ---- phase 0: stage x rows 0..48 into LDS bf16 [49][132] ----
  #pragma unroll
  for (int p = 0; p < 4; ++p) {
    int L = p * 256 + tid;
    if (L < 784) {                          // 49 rows * 16 chunks
      int r = L >> 4, c = L & 15;
      const float* g = xbase + ((r / 7) * 56 + (r % 7)) * CDIM + c * 8;
      f32x4 x0 = *(const f32x4*)g;
      f32x4 x1 = *(const f32x4*)(g + 4);
      bf16x8 v8;
      v8[0] = (__bf16)x0[0]; v8[1] = (__bf16)x0[1]; v8[2] = (__bf16)x0[2]; v8[3] = (__bf16)x0[3];
      v8[4] = (__bf16)x1[0]; v8[5] = (__bf16)x1[1]; v8[6] = (__bf16)x1[2]; v8[7] = (__bf16)x1[3];
      *(bf16x8*)(xo_ + r * (QS2 * 2) + c * 16) = v8;
    }
  }

  __syncthreads();   // [1] x tile ready

  // ---- K-pass: K^T fragments (ch rows, tok cols) for THIS head's 32 channels ----
  unsigned pkk[4][2][2];   // [mt][ct][t]: K[ch=hc+ct*16+lg*4+2t(+1)][tok=mt*16+l15]
  {
    bf16x8 aw[2][4];
    #pragma unroll
    for (int ct = 0; ct < 2; ++ct)
      #pragma unroll
      for (int kt = 0; kt < 4; ++kt)
        aw[ct][kt] = *(const bf16x8*)(qkvT + (CDIM + hc + ct * 16 + l15) * CDIM + kt * 32 + lg * 8);
    f32x4 kb[2];
    kb[0] = *(const f32x4*)(qkv_b + CDIM + hc + lg * 4);
    kb[1] = *(const f32x4*)(qkv_b + CDIM + hc + 16 + lg * 4);
    #pragma unroll
    for (int mt = 0; mt < 4; ++mt) {
      bf16x8 a[4];
      #pragma unroll
      for (int kt = 0; kt < 4; ++kt)
        a[kt] = *(const bf16x8*)(xo_ + rb[mt] + kt * 64 + lg * 16);
      #pragma unroll
      for (int ct = 0; ct < 2; ++ct) {
        f32x4 ck; ck[0]=0.f; ck[1]=0.f; ck[2]=0.f; ck[3]=0.f;
        #pragma unroll
        for (int kt = 0; kt < 4; ++kt) ck = mfma32(aw[ct][kt], a[kt], ck);
        pkk[mt][ct][0] = pkbf(ck[0] + kb[ct][0], ck[1] + kb[ct][1]);
        pkk[mt][ct][1] = pkbf(ck[2] + kb[ct][2], ck[3] + kb[ct][3]);
      }
    }
  }

  // ---- transpose K fragments to QK A-frags in-register (8 shfl + 4 sel per nt) ----
  bf16x8 akf[4];           // lane(l15=tok nt*16+l15, lg): elem j -> ch hc+lg*8+j
  #pragma unroll
  for (int nt = 0; nt < 4; ++nt) {
    unsigned w[4];
    #pragma unroll
    for (int d = 0; d < 4; ++d) {
      int srcl = ((lg & 1) * 2 + (d >> 1)) * 16 + l15;
      unsigned w0 = __shfl(pkk[nt][0][d & 1], srcl);
      unsigned w1 = __shfl(pkk[nt][1][d & 1], srcl);
      w[d] = (lane >= 32) ? w1 : w0;
    }
    uint4 u; u.x = w[0]; u.y = w[1]; u.z = w[2]; u.w = w[3];
    akf[nt] = __builtin_bit_cast(bf16x8, u);
  }

  // ---- V-pass: V^T[ch][tok] into wave-local LDS strip (fragment layout needs transpose;
  //      cheap wave-local round-trip, no barrier: same-wave LDS RAW is ordered) ----
  {
    bf16x8 aw[2][4];
    #pragma unroll
    for (int ct = 0; ct < 2; ++ct)
      #pragma unroll
      for (int kt = 0; kt < 4; ++kt)
        aw[ct][kt] = *(const bf16x8*)(qkvT + (2 * CDIM + hc + ct * 16 + l15) * CDIM + kt * 32 + lg * 8);
    f32x4 vb[2];
    vb[0] = *(const f32x4*)(qkv_b + 2 * CDIM + hc + lg * 4);
    vb[1] = *(const f32x4*)(qkv_b + 2 * CDIM + hc + 16 + lg * 4);
    #pragma unroll
    for (int mt = 0; mt < 4; ++mt) {
      const int tok = mt * 16 + l15;
      bf16x8 a[4];
      #pragma unroll
      for (int kt = 0; kt < 4; ++kt)
        a[kt] = *(const bf16x8*)(xo_ + rb[mt] + kt * 64 + lg * 16);
      f32x4 cv[2];
      #pragma unroll
      for (int ct = 0; ct < 2; ++ct) {
        cv[ct][0]=0.f; cv[ct][1]=0.f; cv[ct][2]=0.f; cv[ct][3]=0.f;
        #pragma unroll
        for (int kt = 0; kt < 4; ++kt) cv[ct] = mfma32(aw[ct][kt], a[kt], cv[ct]);
      }
      if (tok <= 48) {
        #pragma unroll
        for (int ct = 0; ct < 2; ++ct)
          #pragma unroll
          for (int i = 0; i < 4; ++i)
            vTw[(ct * 16 + lg * 4 + i) * TSV + tok] = (__bf16)(cv[ct][i] + vb[ct][i]);
      } else if (tok <= 51) {               // zero cols 49..51 (clamped PV b64 reach)
        #pragma unroll
        for (int ct = 0; ct < 2; ++ct)
          #pragma unroll
          for (int i = 0; i < 4; ++i)
            vTw[(ct * 16 + lg * 4 + i) * TSV + tok] = (__bf16)0.0f;
      }
    }
  }

  // ---- Q-pass: this head's Q^T fragments, register-resident packed ----
  unsigned pkq[4][2][2];   // [mt][ct][t]: Q[ch=hc+ct*16+lg*4+2t(+1)][tok=mt*16+l15]
  {
    bf16x8 aw[2][4];
    #pragma unroll
    for (int ct = 0; ct < 2; ++ct)
      #pragma unroll
      for (int kt = 0; kt < 4; ++kt)
        aw[ct][kt] = *(const bf16x8*)(qkvT + (hc + ct * 16 + l15) * CDIM + kt * 32 + lg * 8);
    f32x4 qb[2];
    qb[0] = *(const f32x4*)(qkv_b + hc + lg * 4);
    qb[1] = *(const f32x4*)(qkv_b + hc + 16 + lg * 4);
    #pragma unroll
    for (int ct = 0; ct < 2; ++ct)
      #pragma unroll
      for (int i = 0; i < 4; ++i) qb[ct][i] *= SC2;   // match pre-scaled q weights
    #pragma unroll
    for (int mt = 0; mt < 4; ++mt) {
      bf16x8 a[4];
      #pragma unroll
      for (int kt = 0; kt < 4; ++kt)
        a[kt] = *(const bf16x8*)(xo_ + rb[mt] + kt * 64 + lg * 16);
      #pragma unroll
      for (int ct = 0; ct < 2; ++ct) {
        f32x4 qc; qc[0]=0.f; qc[1]=0.f; qc[2]=0.f; qc[3]=0.f;
        #pragma unroll
        for (int kt = 0; kt < 4; ++kt) qc = mfma32(aw[ct][kt], a[kt], qc);
        pkq[mt][ct][0] = pkbf(qc[0] + qb[ct][0], qc[1] + qb[ct][1]);
        pkq[mt][ct][1] = pkbf(qc[2] + qb[ct][2], qc[3] + qb[ct][3]);
      }
    }
  }

  __syncthreads();   // [2] all x reads done -> O may overlay xo_

  // ---- phase 2: attention; wave handles all 4 q-tiles of its head ----
  const float* blh = blut + wave * 4096;
  #pragma unroll
  for (int mi = 0; mi < 4; ++mi) {
    const int m0 = mi * 16;

    // assemble Q B-frag from pkq via 8 shfl + 4 select (r3-verified mapping)
    unsigned w[4];
    #pragma unroll
    for (int d = 0; d < 4; ++d) {
      int srcl = ((lg & 1) * 2 + (d >> 1)) * 16 + l15;
      unsigned w0 = __shfl(pkq[mi][0][d & 1], srcl);
      unsigned w1 = __shfl(pkq[mi][1][d & 1], srcl);
      w[d] = (lane >= 32) ? w1 : w0;
    }
    uint4 u; u.x = w[0]; u.y = w[1]; u.z = w[2]; u.w = w[3];
    bf16x8 bq8 = __builtin_bit_cast(bf16x8, u);

    float psum = 0.f;
    bf16x4 pa4[4];                         // P^T fragments, in-lane
    #pragma unroll
    for (int nt = 0; nt < 4; ++nt) {
      f32x4 bias = *(const f32x4*)(blh + (m0 + l15) * 64 + nt * 16 + lg * 4);
      f32x4 z; z[0]=0.f; z[1]=0.f; z[2]=0.f; z[3]=0.f;
      f32x4 s = mfma32(akf[nt], bq8, z);   // S^T[tok=nt*16+lg*4+i][q=m0+l15]
      float e0 = exp2f(s[0] + bias[0]);
      float e1 = exp2f(s[1] + bias[1]);
      float e2 = exp2f(s[2] + bias[2]);
      float e3 = exp2f(s[3] + bias[3]);
      psum += (e0 + e1) + (e2 + e3);
      uint2 pw; pw.x = pkbf(e0, e1); pw.y = pkbf(e2, e3);
      pa4[nt] = __builtin_bit_cast(bf16x4, pw);
    }
    psum += __shfl_xor(psum, 16);          // reduce over lg groups (same q column)
    psum += __shfl_xor(psum, 32);
    const float inv = __builtin_amdgcn_rcpf(psum);

    // PV as O^T = V^T * P^T, K=16 emulated (pa zero-padded, V dup-padded)
    f32x4 ot0, ot1;
    ot0[0]=0.f; ot0[1]=0.f; ot0[2]=0.f; ot0[3]=0.f;
    ot1[0]=0.f; ot1[1]=0.f; ot1[2]=0.f; ot1[3]=0.f;
    const __bf16* vrow0 = vTw + l15 * TSV;
    const __bf16* vrow1 = vrow0 + 16 * TSV;
    #pragma unroll
    for (int nt = 0; nt < 4; ++nt) {
      int tb = nt * 16 + lg * 4; if (tb > 48) tb = 48;
      bf16x8 pb8 = zpad8(pa4[nt]);
      bf16x4 v0 = *(const bf16x4*)(vrow0 + tb);
      bf16x4 v1 = *(const bf16x4*)(vrow1 + tb);
      ot0 = mfma32(dup8(v0), pb8, ot0);
      ot1 = mfma32(dup8(v1), pb8, ot1);
    }
    const int rq = m0 + l15;
    if (rq <= 48) {
      bf16x4 o4a, o4b;
      #pragma unroll
      for (int i = 0; i < 4; ++i) {
        o4a[i] = (__bf16)(ot0[i] * inv);
        o4b[i] = (__bf16)(ot1[i] * inv);
      }
      char* orow = xo_ + rq * (QS2 * 2);
      *(bf16x4*)(orow + (hc + lg * 4) * 2)      = o4a;  // b64 stores, 8B-aligned
      *(bf16x4*)(orow + (hc + 16 + lg * 4) * 2) = o4b;
    }
  }

  __syncthreads();   // [3] O ready across waves

  // ---- phase 3: proj GEMM; wave owns 32 output cols (2 ct tiles) ----
  bf16x8 bp[2][4];
  #pragma unroll
  for (int ct = 0; ct < 2; ++ct)
    #pragma unroll
    for (int kt = 0; kt < 4; ++kt)
      bp[ct][kt] = *(const bf16x8*)(projT + (hc + ct * 16 + l15) * CDIM + kt * 32 + lg * 8);
  float pbs[2];
  pbs[0] = proj_b[hc + l15];
  pbs[1] = proj_b[hc + 16 + l15];

  float* outw = out + (((b * 56) + wh * 7) * 56 + ww * 7) * CDIM;
  #pragma unroll
  for (int mt = 0; mt < 4; ++mt) {
    bf16x8 ao[4];
    #pragma unroll
    for (int kt = 0; kt < 4; ++kt)
      ao[kt] = *(const bf16x8*)(xo_ + rb[mt] + kt * 64 + lg * 16);
    #pragma unroll
    for (int ct = 0; ct < 2; ++ct) {
      f32x4 c0; c0[0]=0.f; c0[1]=0.f; c0[2]=0.f; c0[3]=0.f;
      #pragma unroll
      for (int kt = 0; kt < 4; ++kt) c0 = mfma32(ao[kt], bp[ct][kt], c0);
      #pragma unroll
      for (int i = 0; i < 4; ++i) {
        const int r = mt * 16 + lg * 4 + i;
        if (r < NTOK) {
          float* po = outw + ((r / 7) * 56 + (r % 7)) * CDIM + hc + ct * 16;
          po[l15] = c0[i] + pbs[ct];
        }
      }
    }
  }
}

extern "C" void kernel_launch(void* const* d_in, const int* in_sizes, int n_in,
                              void* d_out, int out_size, void* d_ws, size_t ws_size,
                              hipStream_t stream) {
  const float* x      = (const float*)d_in[0];
  const float* qkv_b  = (const float*)d_in[2];
  const float* proj_b = (const float*)d_in[4];

  hipLaunchKernelGGL(prep_kernel, dim3(320), dim3(256), 0, stream,
                     (const float*)d_in[1], (const float*)d_in[3], (const float*)d_in[5],
                     (__bf16*)d_ws, (__bf16*)((char*)d_ws + 98304),
                     (float*)((char*)d_ws + 131072));
  hipLaunchKernelGGL(attn_kernel, dim3(4096), dim3(256), 0, stream,
                     x, qkv_b, proj_b, (const char*)d_ws, (float*)d_out);
}